// Round 3
// baseline (4252.966 us; speedup 1.0000x reference)
//
#include <hip/hip_runtime.h>
#include <stdint.h>

typedef unsigned short u16;
typedef __bf16 bf16x8 __attribute__((ext_vector_type(8)));
typedef float f32x4 __attribute__((ext_vector_type(4)));

#define N_X   20000
#define NNODE 24264
#define NEDGE 120000
#define MPAD  24320   // 190 * 128
#define NBINS (NNODE * 4)

__device__ inline float b2f(u16 u) {
  union { uint32_t u; float f; } x; x.u = ((uint32_t)u) << 16; return x.f;
}
__device__ inline u16 f2b(float f) {
  union { float f; uint32_t u; } x; x.f = f;
  uint32_t r = x.u + 0x7FFFu + ((x.u >> 16) & 1u);
  return (u16)(r >> 16);
}

__device__ inline void load16_lds(const void* g, void* s) {
  __builtin_amdgcn_global_load_lds(
      (const __attribute__((address_space(1))) void*)g,
      (__attribute__((address_space(3))) void*)s, 16, 0, 0);
}

// ---------------------------------------------------------------------------
// GEMM core (m97 structure): C[M][N] = A[M][K] * Bt[N][K]^T, bf16 in, f32 acc
// 128x128 tile, BK=64, 256 thr = 4 waves (2x2), wave = 64x64 (4x4 frags)
// EPI 0: f32 store (bounds realM/realN)   EPI 1: bf16 plain store
// EPI 2: bf16 store with bias[col]+relu (col<realN else 0)
// ---------------------------------------------------------------------------
template<int EPI>
__device__ inline void gemm_body(const u16* __restrict__ A, int lda,
                                 const u16* __restrict__ Bt, int ldb,
                                 void* __restrict__ Cp, int ldc, int nk,
                                 const float* __restrict__ bias,
                                 int realM, int realN,
                                 size_t m0, size_t n0,
                                 u16* smA, u16* smB)
{
  const int tid = threadIdx.x;
  const int w = tid >> 6, lane = tid & 63;
  const int l15 = lane & 15, lk = lane >> 4;
  const int wm = w >> 1, wn = w & 1;

  const u16* ga = A  + (m0 + (tid >> 3)) * (size_t)lda + (tid & 7) * 8;
  const u16* gb = Bt + (n0 + (tid >> 3)) * (size_t)ldb + (tid & 7) * 8;

  f32x4 acc[4][4];
  const f32x4 zero = {0.f, 0.f, 0.f, 0.f};
#pragma unroll
  for (int i = 0; i < 4; ++i)
#pragma unroll
    for (int j = 0; j < 4; ++j) acc[i][j] = zero;

  const u16* pa = smA + (wm * 64 + l15) * 64 + lk * 8;
  const u16* pb = smB + (wn * 64 + l15) * 64 + lk * 8;

  for (int kt = 0; kt < nk; ++kt) {
#pragma unroll
    for (int rd = 0; rd < 4; ++rd) {
      load16_lds(ga + (size_t)rd * 32 * lda, smA + rd * 2048 + w * 512);
      load16_lds(gb + (size_t)rd * 32 * ldb, smB + rd * 2048 + w * 512);
    }
    ga += 64; gb += 64;
    __syncthreads();
#pragma unroll
    for (int kk = 0; kk < 2; ++kk) {
      bf16x8 av[4], bv[4];
#pragma unroll
      for (int f = 0; f < 4; ++f) {
        av[f] = *(const bf16x8*)(pa + f * 1024 + kk * 32);
        bv[f] = *(const bf16x8*)(pb + f * 1024 + kk * 32);
      }
#pragma unroll
      for (int i = 0; i < 4; ++i)
#pragma unroll
        for (int j = 0; j < 4; ++j)
          acc[i][j] = __builtin_amdgcn_mfma_f32_16x16x32_bf16(av[i], bv[j], acc[i][j], 0, 0, 0);
    }
    __syncthreads();
  }

  const int crow = wm * 64 + lk * 4;
  const int ccol = wn * 64 + l15;
#pragma unroll
  for (int i = 0; i < 4; ++i) {
#pragma unroll
    for (int q = 0; q < 4; ++q) {
      size_t row = m0 + crow + i * 16 + q;
#pragma unroll
      for (int j = 0; j < 4; ++j) {
        int col = (int)n0 + ccol + j * 16;
        float v = acc[i][j][q];
        if constexpr (EPI == 0) {
          if ((int)row < realM && col < realN)
            ((float*)Cp)[row * (size_t)ldc + col] = v;
        } else if constexpr (EPI == 1) {
          ((u16*)Cp)[row * (size_t)ldc + col] = f2b(v);
        } else {
          float bb = (col < realN) ? bias[col] : 0.f;
          v = (col < realN) ? v + bb : 0.f;
          v = v > 0.f ? v : 0.f;
          ((u16*)Cp)[row * (size_t)ldc + col] = f2b(v);
        }
      }
    }
  }
}

template<int EPI>
__global__ __launch_bounds__(256)
void gemm_bt(const u16* __restrict__ A, int lda,
             const u16* __restrict__ Bt, int ldb,
             void* __restrict__ Cp, int ldc, int nk,
             const float* __restrict__ bias, int realM, int realN)
{
  __shared__ u16 smA[128 * 64];
  __shared__ u16 smB[128 * 64];
  gemm_body<EPI>(A, lda, Bt, ldb, Cp, ldc, nk, bias, realM, realN,
                 (size_t)blockIdx.y * 128, (size_t)blockIdx.x * 128, smA, smB);
}

// 1-D grid, bijective XCD-chunked swizzle (m204), cols-fast within chunk.
template<int EPI>
__global__ __launch_bounds__(256)
void gemm_bt_swz(const u16* __restrict__ A, int lda,
                 const u16* __restrict__ Bt, int ldb,
                 void* __restrict__ Cp, int ldc, int nk,
                 const float* __restrict__ bias, int CB, int nwg, int realN)
{
  __shared__ u16 smA[128 * 64];
  __shared__ u16 smB[128 * 64];
  int orig = blockIdx.x;
  int q = nwg >> 3, r = nwg & 7;
  int xcd = orig & 7, li = orig >> 3;
  int wgid = (xcd < r ? xcd * (q + 1) : r * (q + 1) + (xcd - r) * q) + li;
  int brow = wgid / CB, bcol = wgid - brow * CB;
  gemm_body<EPI>(A, lda, Bt, ldb, Cp, ldc, nk, bias, 0, realN,
                 (size_t)brow * 128, (size_t)bcol * 128, smA, smB);
}

// ---------------------------------------------------------------------------
// pack h = concat(x, gene) -> bf16 [MPAD][ld] (cols 0..1663, zero padded)
// ---------------------------------------------------------------------------
__global__ void pack_h(const float* __restrict__ x, const float* __restrict__ g,
                       u16* __restrict__ h, int ld)
{
  int col = blockIdx.x * 256 + threadIdx.x;
  int row = blockIdx.y;
  if (col >= 1664) return;
  float v = 0.f;
  if (col < 1613) {
    if (row < N_X)        v = x[(size_t)row * 1613 + col];
    else if (row < NNODE) v = g[(size_t)(row - N_X) * 1613 + col];
  }
  h[(size_t)row * ld + col] = f2b(v);
}

// ---------------------------------------------------------------------------
// transpose-pack: W[Ksrc][Nsrc] f32 -> Bt[n*ldK + k] bf16 for k<Kchunk,n<Npad
// ---------------------------------------------------------------------------
__global__ void pack_bt(const float* __restrict__ W, int Ksrc, int Nsrc,
                        u16* __restrict__ Bt, int ldK, int Kchunk, int Npad)
{
  __shared__ float t[32][33];
  int tx = threadIdx.x & 31, ty = threadIdx.x >> 5;  // 32 x 8
  int k0 = blockIdx.y * 32, n0 = blockIdx.x * 32;
#pragma unroll
  for (int i = 0; i < 32; i += 8) {
    int k = k0 + ty + i, n = n0 + tx;
    t[ty + i][tx] = (k < Ksrc && n < Nsrc) ? W[(size_t)k * Nsrc + n] : 0.f;
  }
  __syncthreads();
#pragma unroll
  for (int i = 0; i < 32; i += 8) {
    int n = n0 + ty + i, k = k0 + tx;
    if (n < Npad && k < Kchunk) Bt[(size_t)n * ldK + k] = f2b(t[tx][ty + i]);
  }
}

// ---------------------------------------------------------------------------
// degree per (dst,rel) bin; inverse; scan; CSR fill sorted by (dst,rel)
// ---------------------------------------------------------------------------
__global__ void count_deg4(const int* __restrict__ ei, const int* __restrict__ et,
                           int* __restrict__ deg4)
{
  int e = blockIdx.x * 256 + threadIdx.x;
  if (e < NEDGE) atomicAdd(&deg4[(size_t)ei[NEDGE + e] * 4 + et[e]], 1);
}

__global__ void make_inv_i(const int* __restrict__ deg4, float* __restrict__ inv, int n)
{
  int i = blockIdx.x * 256 + threadIdx.x;
  if (i < n) inv[i] = 1.f / (float)(deg4[i] > 1 ? deg4[i] : 1);
}

// exclusive prefix scan of deg4[NBINS] -> off4[NBINS+1], single block 1024 thr
__global__ void scan_deg(const int* __restrict__ deg, int* __restrict__ off)
{
  __shared__ int s[1024];
  int t = threadIdx.x;
  const int per = (NBINS + 1023) / 1024;
  int start = t * per;
  int end = start + per; if (end > NBINS) end = NBINS;
  int sum = 0;
  for (int i = start; i < end; ++i) sum += deg[i];
  s[t] = sum;
  __syncthreads();
  for (int d = 1; d < 1024; d <<= 1) {
    int v = (t >= d) ? s[t - d] : 0;
    __syncthreads();
    s[t] += v;
    __syncthreads();
  }
  int run = s[t] - sum;
  for (int i = start; i < end; ++i) { off[i] = run; run += deg[i]; }
  if (t == 1023) off[NBINS] = s[1023];
}

__global__ void fill_csr2(const int* __restrict__ ei, const int* __restrict__ et,
                          const int* __restrict__ off4, int* __restrict__ cur,
                          u16* __restrict__ srcidx)
{
  int e = blockIdx.x * 256 + threadIdx.x;
  if (e < NEDGE) {
    int bin = ei[NEDGE + e] * 4 + et[e];
    int p = off4[bin] + atomicAdd(&cur[bin], 1);
    srcidx[p] = (u16)ei[e];
  }
}

// ---------------------------------------------------------------------------
// Gather-mean aggregation into stacked A matrix:
//   Ab[row][(1+r)*CH + c] = bf16( inv[row,r] * sum_{src in N_r(row)} hsrc[src][c] )
// COPY0: also Ab[row][c] = hsrc[row][c] (chunk 0 = own features).
// One block per row; edge srcs (sorted by rel) cached in LDS.
// ---------------------------------------------------------------------------
template<int COPY0>
__global__ __launch_bounds__(256)
void agg_gather(const u16* __restrict__ hsrc, int ldh,
                u16* __restrict__ Ab, int lda, int CH,
                const float* __restrict__ inv, const int* __restrict__ off4,
                const u16* __restrict__ srcidx)
{
  int row = blockIdx.x, tid = threadIdx.x;
  size_t abase = (size_t)row * lda;
  if (row >= NNODE) {  // pad rows -> zeros (chunk0 handled by pack_h when !COPY0)
    int c0 = COPY0 ? 0 : CH;
    for (int c = c0 + tid; c < 5 * CH; c += 256) Ab[abase + c] = 0;
    return;
  }
  __shared__ u16  s_src[512];
  __shared__ int  s_b[5];
  __shared__ float s_w[4];
  if (tid < 5) s_b[tid] = off4[row * 4 + tid];
  if (tid < 4) s_w[tid] = inv[row * 4 + tid];
  __syncthreads();
  int e0 = s_b[0], ne = s_b[4] - e0;
  int nl = ne < 512 ? ne : 512;
  for (int j = tid; j < nl; j += 256) s_src[j] = srcidx[e0 + j];
  __syncthreads();
  const bool fits = (ne <= 512);
  for (int c = tid; c < CH; c += 256) {
    if (COPY0) Ab[abase + c] = hsrc[(size_t)row * ldh + c];
#pragma unroll
    for (int r = 0; r < 4; ++r) {
      int jb = s_b[r] - e0, je = s_b[r + 1] - e0;
      float a = 0.f;
      if (fits) {
        for (int j = jb; j < je; ++j)
          a += b2f(hsrc[(size_t)s_src[j] * ldh + c]);
      } else {
        for (int j = jb; j < je; ++j)
          a += b2f(hsrc[(size_t)srcidx[e0 + j] * ldh + c]);
      }
      Ab[abase + (size_t)(1 + r) * CH + c] = f2b(a * s_w[r]);
    }
  }
}

// ---------------------------------------------------------------------------
// fallback-path kernels (round-1 verified flow)
// ---------------------------------------------------------------------------
__global__ void scatter_rel(const u16* __restrict__ Hr, int ldH, int C,
                            const int* __restrict__ ei, const int* __restrict__ et,
                            const float* __restrict__ inv,
                            float* __restrict__ agg, int r)
{
  int e = blockIdx.x;
  if (et[e] != r) return;
  int src = ei[e], dst = ei[NEDGE + e];
  float wgt = inv[(size_t)dst * 4 + r];
  const u16* hrow = Hr + (size_t)src * ldH;
  float* arow = agg + (size_t)dst * C;
  for (int c = threadIdx.x; c < C; c += blockDim.x)
    atomicAdd(&arow[c], b2f(hrow[c]) * wgt);
}

__global__ void finalize_relu(const float* __restrict__ agg, int C,
                              const float* __restrict__ bias,
                              u16* __restrict__ h, int ldh)
{
  int col = blockIdx.x * 256 + threadIdx.x;
  int row = blockIdx.y;
  if (col >= ldh) return;
  float v = 0.f;
  if (row < NNODE && col < C) {
    v = agg[(size_t)row * C + col] + bias[col];
    v = v > 0.f ? v : 0.f;
  }
  h[(size_t)row * ldh + col] = f2b(v);
}

// ---------------------------------------------------------------------------
// head: z = H3[row][0:400] @ lin2 + b ; out = log_softmax(z)
// ---------------------------------------------------------------------------
__global__ void head_out(const u16* __restrict__ H3, int ld,
                         const float* __restrict__ w2, const float* __restrict__ b2,
                         float* __restrict__ out)
{
  int row = blockIdx.x * 256 + threadIdx.x;
  if (row >= NNODE) return;
  const u16* h = H3 + (size_t)row * ld;
  float z0 = b2[0], z1 = b2[1];
  for (int k = 0; k < 400; ++k) {
    float v = b2f(h[k]);
    z0 = fmaf(v, w2[2 * k], z0);
    z1 = fmaf(v, w2[2 * k + 1], z1);
  }
  float m = fmaxf(z0, z1);
  float lse = m + logf(expf(z0 - m) + expf(z1 - m));
  out[(size_t)row * 2]     = z0 - lse;
  out[(size_t)row * 2 + 1] = z1 - lse;
}

// ---------------------------------------------------------------------------
extern "C" void kernel_launch(void* const* d_in, const int* in_sizes, int n_in,
                              void* d_out, int out_size, void* d_ws, size_t ws_size,
                              hipStream_t stream)
{
  const float* x     = (const float*)d_in[0];
  const int*   ei    = (const int*)d_in[1];
  const int*   et    = (const int*)d_in[2];
  const float* gene  = (const float*)d_in[3];
  const float* W1    = (const float*)d_in[4];
  const float* root1 = (const float*)d_in[5];
  const float* b1    = (const float*)d_in[6];
  const float* W2    = (const float*)d_in[7];
  const float* root2 = (const float*)d_in[8];
  const float* b2v   = (const float*)d_in[9];
  const float* l1w   = (const float*)d_in[10];
  const float* l1b   = (const float*)d_in[11];
  const float* l2w   = (const float*)d_in[12];
  const float* l2b   = (const float*)d_in[13];
  (void)in_sizes; (void)n_in; (void)out_size;

  char* ws = (char*)d_ws;
  size_t off_b = 0;
  auto alloc = [&](size_t bytes) {
    void* p = ws + off_b;
    off_b += (bytes + 255) & ~(size_t)255;
    return p;
  };

  // shared small arrays
  int*   deg4   = (int*)alloc((size_t)NBINS * 4);        // later reused as `cur`
  int*   off4   = (int*)alloc((size_t)(NBINS + 1) * 4);
  float* inv    = (float*)alloc((size_t)NBINS * 4);
  u16*   srcidx = (u16*)alloc((size_t)NEDGE * 2);

  hipMemsetAsync(deg4, 0, (size_t)NBINS * 4, stream);
  count_deg4<<<(NEDGE + 255) / 256, 256, 0, stream>>>(ei, et, deg4);
  scan_deg<<<1, 1024, 0, stream>>>(deg4, off4);
  make_inv_i<<<(NBINS + 255) / 256, 256, 0, stream>>>(deg4, inv, NBINS);

  const bool big = ws_size >= (size_t)515000000;

  if (big) {
    // hbuf 81MB + Abig 405MB + Bt 27.7MB (+1.6MB small) ~= 514.7MB
    u16* hbuf = (u16*)alloc((size_t)MPAD * 1664 * 2);
    u16* Abig = (u16*)alloc((size_t)MPAD * 8320 * 2);
    u16* Bt   = (u16*)alloc((size_t)1664 * 8320 * 2);

    // CSR sorted by (dst, rel); reuse deg4 as cursor
    int* cur = deg4;
    hipMemsetAsync(cur, 0, (size_t)NBINS * 4, stream);
    fill_csr2<<<(NEDGE + 255) / 256, 256, 0, stream>>>(ei, et, off4, cur, srcidx);

    // ---- Layer 1: A = [h | mean_r(h)] : [MPAD][8320]
    pack_h<<<dim3(7, MPAD), 256, 0, stream>>>(x, gene, Abig, 8320);
    agg_gather<0><<<MPAD, 256, 0, stream>>>(Abig, 8320, Abig, 8320, 1664,
                                            inv, off4, srcidx);
    pack_bt<<<dim3(52, 52), 256, 0, stream>>>(root1, 1613, 1600, Bt, 8320, 1664, 1664);
    for (int r = 0; r < 4; ++r)
      pack_bt<<<dim3(52, 52), 256, 0, stream>>>(W1 + (size_t)r * 1613 * 1600, 1613, 1600,
                                                Bt + (size_t)(1 + r) * 1664, 8320, 1664, 1664);
    {
      int CB = 13, nwg = 190 * CB;  // 2470
      gemm_bt_swz<2><<<nwg, 256, 0, stream>>>(Abig, 8320, Bt, 8320, hbuf, 1664, 130,
                                              b1, CB, nwg, 1600);
    }

    // ---- Layer 2: A = [h2 | mean_r(h2)] : [MPAD][8000]
    agg_gather<1><<<MPAD, 256, 0, stream>>>(hbuf, 1664, Abig, 8000, 1600,
                                            inv, off4, srcidx);
    pack_bt<<<dim3(32, 50), 256, 0, stream>>>(root2, 1600, 900, Bt, 8000, 1600, 1024);
    for (int r = 0; r < 4; ++r)
      pack_bt<<<dim3(32, 50), 256, 0, stream>>>(W2 + (size_t)r * 1600 * 900, 1600, 900,
                                                Bt + (size_t)(1 + r) * 1600, 8000, 1600, 1024);
    {
      int CB = 8, nwg = 190 * CB;  // 1520
      gemm_bt_swz<2><<<nwg, 256, 0, stream>>>(Abig, 8000, Bt, 8000, hbuf, 1664, 125,
                                              b2v, CB, nwg, 900);
    }

    // ---- Head: lin1 (K=960, N=512, real 400) bias+relu -> Abig; then lin2+lsm
    pack_bt<<<dim3(16, 30), 256, 0, stream>>>(l1w, 900, 400, Bt, 960, 960, 512);
    gemm_bt<2><<<dim3(4, 190), 256, 0, stream>>>(hbuf, 1664, Bt, 960, Abig, 512, 15,
                                                 l1b, MPAD, 400);
    head_out<<<(NNODE + 255) / 256, 256, 0, stream>>>((u16*)Abig, 512, l2w, l2b,
                                                      (float*)d_out);
  } else {
    // fallback: round-1 verified flow (~350MB)
    u16*   hbuf = (u16*)alloc((size_t)MPAD * 1664 * 2);
    u16*   hr   = (u16*)alloc((size_t)MPAD * 1664 * 2);
    u16*   bt   = (u16*)alloc((size_t)1664 * 1664 * 2);
    float* agg  = (float*)alloc((size_t)NNODE * 1600 * 4);

    pack_h<<<dim3(7, MPAD), 256, 0, stream>>>(x, gene, hbuf, 1664);

    pack_bt<<<dim3(52, 52), 256, 0, stream>>>(root1, 1613, 1600, bt, 1664, 1664, 1664);
    gemm_bt<0><<<dim3(13, 190), 256, 0, stream>>>(hbuf, 1664, bt, 1664, agg, 1600, 26,
                                                  nullptr, NNODE, 1600);
    for (int r = 0; r < 4; ++r) {
      pack_bt<<<dim3(52, 52), 256, 0, stream>>>(W1 + (size_t)r * 1613 * 1600, 1613, 1600,
                                                bt, 1664, 1664, 1664);
      gemm_bt<1><<<dim3(13, 190), 256, 0, stream>>>(hbuf, 1664, bt, 1664, hr, 1664, 26,
                                                    nullptr, 0, 0);
      scatter_rel<<<NEDGE, 256, 0, stream>>>(hr, 1664, 1600, ei, et, inv, agg, r);
    }
    finalize_relu<<<dim3(7, MPAD), 256, 0, stream>>>(agg, 1600, b1, hbuf, 1664);

    pack_bt<<<dim3(32, 50), 256, 0, stream>>>(root2, 1600, 900, bt, 1600, 1600, 1024);
    gemm_bt<0><<<dim3(8, 190), 256, 0, stream>>>(hbuf, 1664, bt, 1600, agg, 900, 25,
                                                 nullptr, NNODE, 900);
    for (int r = 0; r < 4; ++r) {
      pack_bt<<<dim3(32, 50), 256, 0, stream>>>(W2 + (size_t)r * 1600 * 900, 1600, 900,
                                                bt, 1600, 1600, 1024);
      gemm_bt<1><<<dim3(8, 190), 256, 0, stream>>>(hbuf, 1664, bt, 1600, hr, 1024, 25,
                                                   nullptr, 0, 0);
      scatter_rel<<<NEDGE, 256, 0, stream>>>(hr, 1024, 900, ei, et, inv, agg, r);
    }
    finalize_relu<<<dim3(4, MPAD), 256, 0, stream>>>(agg, 900, b2v, hbuf, 960);

    pack_bt<<<dim3(16, 30), 256, 0, stream>>>(l1w, 900, 400, bt, 960, 960, 512);
    gemm_bt<2><<<dim3(4, 190), 256, 0, stream>>>(hbuf, 960, bt, 960, hr, 512, 15,
                                                 l1b, MPAD, 400);
    head_out<<<(NNODE + 255) / 256, 256, 0, stream>>>(hr, 512, l2w, l2b, (float*)d_out);
  }
}